// Round 14
// baseline (1065.718 us; speedup 1.0000x reference)
//
#include <hip/hip_runtime.h>
#include <math.h>

#define T_DIM 4096
#define D_DIM 256
#define K_DIM 1024

#define DIFF_OFF 16777216
#define IND_OFF  16777217
#define PERP_OFF 16842753

typedef float f4 __attribute__((ext_vector_type(4)));

// async global load: dst NOT ready until s_waitcnt vmcnt; dst liveness (issue->use)
// forces RA to keep the pipeline registers live. volatile keeps issue order.
#define GLOAD(dst, ptr) asm volatile("global_load_dwordx4 %0, %1, off" : "=v"(dst) : "v"(ptr))
#define WAITV0()        asm volatile("s_waitcnt vmcnt(0)" ::: "memory")
#define SB()            __builtin_amdgcn_sched_barrier(0)

// ---------------- K1: transpose emb [D,K] -> embT [K,D], compute E_k = sum_d emb[d][k]^2
__global__ void k_transpose(const float* __restrict__ emb, float* __restrict__ embT,
                            float* __restrict__ E) {
    int k = blockIdx.x * 256 + threadIdx.x;   // 1024 codes total
    float e = 0.f;
    for (int d = 0; d < D_DIM; ++d) {
        float v = emb[d * K_DIM + k];         // coalesced across k
        embT[k * D_DIM + d] = v;
        e = fmaf(v, v, e);
    }
    E[k] = e;
}

// ---------------- K2: per-row argmin over K codes
// v6: rounds 8/10/12 proved the compiler de-pipelines C-level double-buffering
// (VGPR 60->19.5% busy; 128->31.6%; cap-lift to 256 still allocates 128).
// Explicit control: inline-asm global_load_dwordx4 + sched_barrier(0) fences +
// s_waitcnt vmcnt(0) AFTER each 256-FMA block -> 8 loads in flight under every
// FMA block (512 issue-cycles > ~300cyc L2 latency).
__launch_bounds__(256, 2)
__global__ void k_argmin(const float* __restrict__ x, const float* __restrict__ embT,
                         const float* __restrict__ E, float* __restrict__ indf,
                         unsigned* __restrict__ counts) {
    __shared__ float  xs[64][260];     // 64 rows x 256 D, pad 260 -> conflict-free frag reads
    __shared__ double sred[256];
    __shared__ float  sS[64];

    const int tid = threadIdx.x;
    const int n0  = blockIdx.x * 64;          // 64 rows per block, all within one b
    const int b   = n0 >> 12;                 // T=4096
    const int t0  = n0 & 4095;
    const float* xb = x + (size_t)b * (D_DIM * (size_t)T_DIM) + t0;

    // stage x tile transposed: xs[t][d]; coalesced along t
    for (int m = 0; m < 64; ++m) {
        int idx = tid + 256 * m;
        int d = idx >> 6, tt = idx & 63;
        xs[tt][d] = xb[(size_t)d * T_DIM + tt];
    }
    __syncthreads();

    // S_row = sum_d x^2 (f64 accumulate, single round to f32) — unchanged, bit-validated
    {
        int row = tid >> 2, seg = tid & 3;
        double s = 0.0;
        for (int q = 0; q < 16; ++q) {
            float4 v = *(const float4*)&xs[row][seg * 64 + 4 * q];
            s += (double)v.x * v.x + (double)v.y * v.y + (double)v.z * v.z + (double)v.w * v.w;
        }
        sred[tid] = s;
    }
    __syncthreads();
    if (tid < 64)
        sS[tid] = (float)(sred[4 * tid] + sred[4 * tid + 1] + sred[4 * tid + 2] + sred[4 * tid + 3]);
    __syncthreads();

    const int tc = tid & 31;   // 32 code groups x 8 codes = 256 codes per chunk
    const int tr = tid >> 5;   // 8 row groups x 8 rows = 64 rows

    float bmin[8], Sr[8];
    int   bidx[8];
#pragma unroll
    for (int i = 0; i < 8; ++i) { bmin[i] = INFINITY; bidx[i] = 0; Sr[i] = sS[tr * 8 + i]; }

    for (int chunk = 0; chunk < 4; ++chunk) {
        const int kbase = chunk * 256 + tc * 8;
        const f4* c4 = (const f4*)(embT + (size_t)kbase * D_DIM);

        float acc[8][8];
#pragma unroll
        for (int i = 0; i < 8; ++i)
#pragma unroll
            for (int j = 0; j < 8; ++j) acc[i][j] = 0.f;

        f4 cvA[8], cvB[8];
        // chunk prologue: preload dq=0 into cvA
#pragma unroll
        for (int j = 0; j < 8; ++j) GLOAD(cvA[j], c4 + j * 64);
        WAITV0(); SB();

#pragma unroll 1
        for (int dq2 = 0; dq2 < 32; ++dq2) {
            const int dq = 2 * dq2;
            // issue loads for dq+1 -> cvB (in flight during FMA(A))
#pragma unroll
            for (int j = 0; j < 8; ++j) GLOAD(cvB[j], c4 + j * 64 + dq + 1);
            SB();
            {   // FMA block on cvA (dq)
                float4 xv[8];
#pragma unroll
                for (int i = 0; i < 8; ++i) xv[i] = *(const float4*)&xs[tr * 8 + i][4 * dq];
#pragma unroll
                for (int i = 0; i < 8; ++i)
#pragma unroll
                    for (int j = 0; j < 8; ++j) {
                        acc[i][j] = fmaf(xv[i].x, cvA[j].x, acc[i][j]);
                        acc[i][j] = fmaf(xv[i].y, cvA[j].y, acc[i][j]);
                        acc[i][j] = fmaf(xv[i].z, cvA[j].z, acc[i][j]);
                        acc[i][j] = fmaf(xv[i].w, cvA[j].w, acc[i][j]);
                    }
            }
            SB(); WAITV0(); SB();          // cvB now ready

            // issue loads for dq+2 -> cvA (in flight during FMA(B)); skip on last
            // iteration (an unused asm dst would be dead-range -> RA clobber race)
            if (dq2 != 31) {
#pragma unroll
                for (int j = 0; j < 8; ++j) GLOAD(cvA[j], c4 + j * 64 + dq + 2);
            }
            SB();
            {   // FMA block on cvB (dq+1)
                float4 xv[8];
#pragma unroll
                for (int i = 0; i < 8; ++i) xv[i] = *(const float4*)&xs[tr * 8 + i][4 * dq + 4];
#pragma unroll
                for (int i = 0; i < 8; ++i)
#pragma unroll
                    for (int j = 0; j < 8; ++j) {
                        acc[i][j] = fmaf(xv[i].x, cvB[j].x, acc[i][j]);
                        acc[i][j] = fmaf(xv[i].y, cvB[j].y, acc[i][j]);
                        acc[i][j] = fmaf(xv[i].z, cvB[j].z, acc[i][j]);
                        acc[i][j] = fmaf(xv[i].w, cvB[j].w, acc[i][j]);
                    }
            }
            SB(); WAITV0(); SB();          // next cvA ready
        }

        // epilogue: dist = fl(fl(S - 2*m) + E), strict-< keeps lowest k (k ascends in j, chunk)
#pragma unroll
        for (int j = 0; j < 8; ++j) {
            float Ek = E[kbase + j];
#pragma unroll
            for (int i = 0; i < 8; ++i) {
                float t = fmaf(-2.f, acc[i][j], Sr[i]);  // exact single-rounding of S - 2m
                float dist = t + Ek;
                if (dist < bmin[i]) { bmin[i] = dist; bidx[i] = kbase + j; }
            }
        }
    }

    // half-wave argmin reduce: the 32 threads sharing tr are 32 consecutive lanes,
    // xor masks 1..16 stay within the half-wave. Exact lowest-index tie-break.
#pragma unroll
    for (int i = 0; i < 8; ++i) {
#pragma unroll
        for (int mk = 1; mk <= 16; mk <<= 1) {
            float vo = __shfl_xor(bmin[i], mk, 64);
            int   io = __shfl_xor(bidx[i], mk, 64);
            if (vo < bmin[i] || (vo == bmin[i] && io < bidx[i])) { bmin[i] = vo; bidx[i] = io; }
        }
    }
    if (tc == 0) {
#pragma unroll
        for (int i = 0; i < 8; ++i) {
            indf[n0 + tr * 8 + i] = (float)bidx[i];
            atomicAdd(&counts[bidx[i]], 1u);
        }
    }
}

// ---------------- K3: gather codes, write quant_out (straight-through rounding kept), SSE
__launch_bounds__(256)
__global__ void k_gather(const float* __restrict__ x, const float* __restrict__ embT,
                         const float* __restrict__ indf, float* __restrict__ qout,
                         float* __restrict__ sse) {
    __shared__ int   kk[64];
    __shared__ float cst[256][66];   // [d][t], pad 66 -> 2-way (free) read pattern
    __shared__ float rs[256];

    const int tid = threadIdx.x;
    const int n0  = blockIdx.x * 64;
    const int b   = n0 >> 12;
    const int t0  = n0 & 4095;

    if (tid < 64) kk[tid] = (int)indf[n0 + tid];
    __syncthreads();

    {   // stage gathered code rows transposed into LDS
        int row = tid >> 2, seg = tid & 3;
        const float* cr = embT + (size_t)kk[row] * D_DIM + seg * 64;
        for (int q = 0; q < 16; ++q) {
            float4 v = *(const float4*)(cr + 4 * q);
            int d = seg * 64 + 4 * q;
            cst[d + 0][row] = v.x; cst[d + 1][row] = v.y;
            cst[d + 2][row] = v.z; cst[d + 3][row] = v.w;
        }
    }
    __syncthreads();

    const int lane = tid & 63, w = tid >> 6;
    const size_t base = (size_t)b * (D_DIM * (size_t)T_DIM) + t0 + lane;
    float local = 0.f;
    for (int m = 0; m < 64; ++m) {
        int d = w * 64 + m;
        float xv = x[base + (size_t)d * T_DIM];   // coalesced along t
        float q  = cst[d][lane];
        float dlt = q - xv;                        // quant - x (used for mse)
        qout[base + (size_t)d * T_DIM] = xv + dlt; // straight-through: x + (q - x), keep roundings
        local = fmaf(dlt, dlt, local);
    }

    rs[tid] = local; __syncthreads();
    for (int s = 128; s > 0; s >>= 1) { if (tid < s) rs[tid] += rs[tid + s]; __syncthreads(); }
    if (tid == 0) atomicAdd(sse, rs[0]);
}

// ---------------- K4: scalars (diff, perplexity)
__global__ void k_final(const unsigned* __restrict__ counts, const float* __restrict__ sse,
                        float* __restrict__ out) {
    __shared__ float rs[256];
    int tid = threadIdx.x;
    float local = 0.f;
    for (int q = 0; q < 4; ++q) {
        unsigned c = counts[tid * 4 + q];
        float p = (float)c * (1.f / 65536.f);
        local += p * logf(p + 1e-10f);
    }
    rs[tid] = local; __syncthreads();
    for (int s = 128; s > 0; s >>= 1) { if (tid < s) rs[tid] += rs[tid + s]; __syncthreads(); }
    if (tid == 0) {
        out[PERP_OFF] = expf(-rs[0]);
        float m = *sse * (1.f / 16777216.f);   // mean over B*T*D = 2^24 (exact scale)
        out[DIFF_OFF] = 0.25f * m + m;         // matches fl(0.25*m) + m
    }
}

extern "C" void kernel_launch(void* const* d_in, const int* in_sizes, int n_in,
                              void* d_out, int out_size, void* d_ws, size_t ws_size,
                              hipStream_t stream) {
    const float* x   = (const float*)d_in[0];
    const float* emb = (const float*)d_in[1];
    float* out = (float*)d_out;

    char* w = (char*)d_ws;
    float*    embT   = (float*)(w);                          // 1 MB
    float*    E      = (float*)(w + (1u << 20));             // 4 KB
    unsigned* counts = (unsigned*)(w + (1u << 20) + 4096);   // 4 KB
    float*    sse    = (float*)(w + (1u << 20) + 8192);      // 4 B

    hipMemsetAsync(w + (1u << 20) + 4096, 0, 8192, stream);  // zero counts + sse

    k_transpose<<<dim3(4), dim3(256), 0, stream>>>(emb, embT, E);
    k_argmin  <<<dim3(1024), dim3(256), 0, stream>>>(x, embT, E, out + IND_OFF, counts);
    k_gather  <<<dim3(1024), dim3(256), 0, stream>>>(x, embT, out + IND_OFF, out, sse);
    k_final   <<<dim3(1), dim3(256), 0, stream>>>(counts, sse, out);
}